// Round 19
// baseline (47.150 us; speedup 1.0000x reference)
//
#include <hip/hip_runtime.h>

// FastHST fused: 4-level 1-D scattering, B=32, T=524288, K=16, PAD=8.
// Output: real-contiguous f32 (confirmed r3; harness compares in bf16).
//
// r18 43.5us ref (S1=2048, 6 blk/CU, Karatsuba, balanced tiling, nt stores).
// r19: conv math fdot2 -> v_pk_fma_f16 (even taps in .lo, odd in .hi, one
// hadd at the end). Probe of dot2 rate: issue-count says ~9us of dot2 if
// full-rate, but VALU-busy ~31us (profiled) => dot2 likely half-rate; packed
// f16 FMA is guaranteed full-rate on the packed pipe. f16 accum error ~2e-2
// vs 3x threshold headroom. MFMA rejected by arithmetic (2.7x LDS redundancy
// + 75%-idle epilogue lanes).

using f16x2 = __attribute__((ext_vector_type(2))) __fp16;
using f32x4 = __attribute__((ext_vector_type(4))) float;
using f32x2 = __attribute__((ext_vector_type(2))) float;

static __device__ __forceinline__ uint packh2(float a, float b) {
    f16x2 r = __builtin_amdgcn_cvt_pkrtz(a, b);
    return __builtin_bit_cast(uint, r);
}
static __device__ __forceinline__ uint pkadd(uint a, uint b) {
    f16x2 x = __builtin_bit_cast(f16x2, a);
    f16x2 y = __builtin_bit_cast(f16x2, b);
    f16x2 r = x + y;                           // v_pk_add_f16
    return __builtin_bit_cast(uint, r);
}
static __device__ __forceinline__ f16x2 pkfma(f16x2 f, uint w, f16x2 acc) {
    return f * __builtin_bit_cast(f16x2, w) + acc;   // v_pk_fma_f16
}
static __device__ __forceinline__ float hadd(f16x2 a) {
    return (float)a.x + (float)a.y;
}
static __device__ __forceinline__ void st_nt4(float* p,
                                              float a, float b, float c, float d) {
    f32x4 v; v.x = a; v.y = b; v.z = c; v.w = d;
    __builtin_nontemporal_store(v, reinterpret_cast<f32x4*>(p));
}
static __device__ __forceinline__ void st_nt2(float* p, float a, float b) {
    f32x2 v; v.x = a; v.y = b;
    __builtin_nontemporal_store(v, reinterpret_cast<f32x2*>(p));
}
static __device__ __forceinline__ void st_nt1(float* p, float v) {
    __builtin_nontemporal_store(v, p);
}

constexpr int S1   = 2048;
constexpr int H1   = 56;              // x1 halo each side
constexpr int NPIN = 2168;            // staged complex pairs (4336 floats)
constexpr int NTH  = 256;             // 4 waves

__global__ __launch_bounds__(NTH, 6) void hst_fused_kernel(
    const float* __restrict__ xr, const float* __restrict__ xi,
    const float* __restrict__ psi_r, const float* __restrict__ psi_i,
    const float* __restrict__ phi,
    float* __restrict__ out,
    long o0, long o1, long o2, long o3,
    int L0, int h0, int h1, int h2, int h3)
{
    __shared__ __align__(16) uint REP[NPIN];   // re f16 pairs, 8.7KB
    __shared__ __align__(16) uint IMP[NPIN];   // im pairs, 8.7KB
    __shared__ __align__(16) uint X1P[1080];   // x1: 2160 halfs, 4.3KB
    __shared__ __align__(16) uint X2P[536];    // x2: 1072 halfs, 2.1KB
    __shared__ __align__(16) uint X3P[264];    // x3: 528 halfs, 1.1KB

    const int tid  = threadIdx.x;
    const int wv   = tid >> 6;                // wave 0..3
    const int lane = tid & 63;
    const int gx   = blockIdx.x;
    const int b    = blockIdx.y;
    const int s    = gx * S1;                 // first owned x1 index
    const bool edge = (gx == 0) || (gx == (int)gridDim.x - 1);
    const int X0   = 2 * (s - H1) - 8;        // first staged input idx

    const float* rowr = xr + (size_t)b * (size_t)L0;
    const float* rowi = xi + (size_t)b * (size_t)L0;

    f16x2 FH[8], FR[8], FI[8], FS[8];
    #pragma unroll
    for (int j = 0; j < 8; ++j) {
        FH[j] = __builtin_amdgcn_cvt_pkrtz(phi[2*j],   phi[2*j+1]);
        FR[j] = __builtin_amdgcn_cvt_pkrtz(psi_r[2*j], psi_r[2*j+1]);
        FI[j] = __builtin_amdgcn_cvt_pkrtz(psi_i[2*j], psi_i[2*j+1]);
        FS[j] = __builtin_amdgcn_cvt_pkrtz(psi_r[2*j] + psi_i[2*j],
                                           psi_r[2*j+1] + psi_i[2*j+1]);
    }

    // ---- Phase A: stage input as f16 pairs (tail contiguous 15/wave) ----
    if (!edge) {
        const float4* pr4 = reinterpret_cast<const float4*>(rowr + X0);
        const float4* pi4 = reinterpret_cast<const float4*>(rowi + X0);
        #pragma unroll
        for (int n = 0; n < 4; ++n) {
            const int i = tid + n * NTH;      // 0..1023, all full
            float4 a = pr4[i];
            float4 c = pi4[i];
            uint2 wa; wa.x = packh2(a.x, a.y); wa.y = packh2(a.z, a.w);
            uint2 wc; wc.x = packh2(c.x, c.y); wc.y = packh2(c.z, c.w);
            *reinterpret_cast<uint2*>(&REP[2*i]) = wa;
            *reinterpret_cast<uint2*>(&IMP[2*i]) = wc;
        }
        if (lane < 15) {
            const int i = 1024 + 15 * wv + lane;   // 1024..1083
            float4 a = pr4[i];
            float4 c = pi4[i];
            uint2 wa; wa.x = packh2(a.x, a.y); wa.y = packh2(a.z, a.w);
            uint2 wc; wc.x = packh2(c.x, c.y); wc.y = packh2(c.z, c.w);
            *reinterpret_cast<uint2*>(&REP[2*i]) = wa;
            *reinterpret_cast<uint2*>(&IMP[2*i]) = wc;
        }
    } else {
        for (int i = tid; i < NPIN; i += NTH) {
            int g0 = X0 + 2 * i;
            float r0 = (g0   >= 0 && g0   < L0) ? rowr[g0]   : 0.0f;
            float r1 = (g0+1 >= 0 && g0+1 < L0) ? rowr[g0+1] : 0.0f;
            float i0 = (g0   >= 0 && g0   < L0) ? rowi[g0]   : 0.0f;
            float i1 = (g0+1 >= 0 && g0+1 < L0) ? rowi[g0+1] : 0.0f;
            REP[i] = packh2(r0, r1);
            IMP[i] = packh2(i0, i1);
        }
    }
    __syncthreads();

    // ---- Phase B main: positions 0..2047, two full passes of 4/thread ----
    #pragma unroll
    for (int n = 0; n < 2; ++n) {
        const int g = tid + n * NTH;          // group: positions 4g..4g+3
        const uint4* wp = reinterpret_cast<const uint4*>(&REP[4*g]);
        uint4 a0 = wp[0], a1 = wp[1], a2 = wp[2];
        const uint4* ip = reinterpret_cast<const uint4*>(&IMP[4*g]);
        uint4 c0v = ip[0], c1v = ip[1], c2v = ip[2];
        const uint wr[12] = {a0.x,a0.y,a0.z,a0.w, a1.x,a1.y,a1.z,a1.w, a2.x,a2.y,a2.z,a2.w};
        const uint wi[12] = {c0v.x,c0v.y,c0v.z,c0v.w, c1v.x,c1v.y,c1v.z,c1v.w, c2v.x,c2v.y,c2v.z,c2v.w};
        uint ws12[12];
        #pragma unroll
        for (int j = 0; j < 12; ++j) ws12[j] = pkadd(wr[j], wi[j]);

        float phv[4], mag[4];
        #pragma unroll
        for (int r = 0; r < 4; ++r) {
            f16x2 aS = {}, aA = {}, aB = {}, aC = {};
            #pragma unroll
            for (int j = 0; j < 8; ++j) {
                aS = pkfma(FH[j], wr[r+j], aS);
                aA = pkfma(FR[j], wr[r+j], aA);
                aB = pkfma(FI[j], wi[r+j], aB);
                aC = pkfma(FS[j], ws12[r+j], aC);
            }
            float sh = hadd(aS), A = hadd(aA), Bv = hadd(aB), C = hadd(aC);
            float ur = A - Bv;
            float ui = C - (A + Bv);
            float m2 = sqrtf(fmaf(ur, ur, ui * ui));
            if (edge) {
                int m = s - H1 + 4*g + r;
                m2 = (m >= 0 && m < h0) ? m2 : 0.0f;
            }
            mag[r] = m2;
            phv[r] = sh;
        }
        uint2 xp; xp.x = packh2(mag[0], mag[1]); xp.y = packh2(mag[2], mag[3]);
        *reinterpret_cast<uint2*>(&X1P[2*g]) = xp;

        if (g >= 14) {                        // positions 56.. owned
            long m0 = (long)s - H1 + 4*g;
            st_nt4(out + o0 + (long)b * h0 + m0, phv[0], phv[1], phv[2], phv[3]);
        }
    }

    // ---- Phase B halo: positions 2048..2159, contiguous 28/wave ----
    if (lane < 28) {
        const int h  = 28 * wv + lane;        // 0..111
        const int lm = S1 + h;
        uint wr8[8], wi8[8], ws8[8];
        #pragma unroll
        for (int j = 0; j < 8; ++j) {
            wr8[j] = REP[lm + j]; wi8[j] = IMP[lm + j];
            ws8[j] = pkadd(wr8[j], wi8[j]);
        }
        f16x2 aS = {}, aA = {}, aB = {}, aC = {};
        #pragma unroll
        for (int j = 0; j < 8; ++j) {
            aS = pkfma(FH[j], wr8[j], aS);
            aA = pkfma(FR[j], wr8[j], aA);
            aB = pkfma(FI[j], wi8[j], aB);
            aC = pkfma(FS[j], ws8[j], aC);
        }
        float sh = hadd(aS), A = hadd(aA), Bv = hadd(aB), C = hadd(aC);
        float ur = A - Bv;
        float ui = C - (A + Bv);
        float m2 = sqrtf(fmaf(ur, ur, ui * ui));
        if (edge) {
            int m = s - H1 + lm;
            m2 = (m >= 0 && m < h0) ? m2 : 0.0f;
        }
        reinterpret_cast<__fp16*>(X1P)[lm] = (__fp16)m2;
        if (h < 56)                            // positions 2048..2103 owned
            st_nt1(out + o0 + (long)b * h0 + (s + S1 - H1 + h), sh);
    }
    __syncthreads();

    // ---- Phase C main: positions 0..1023, 4/thread (full) ----
    {
        const int t = tid;
        const uint4* wp = reinterpret_cast<const uint4*>(&X1P[4*t]);
        uint4 a0 = wp[0], a1 = wp[1];
        uint2 u2 = *reinterpret_cast<const uint2*>(&X1P[4*t+8]);
        uint  w10 = X1P[4*t+10];
        const uint w[11] = {a0.x,a0.y,a0.z,a0.w, a1.x,a1.y,a1.z,a1.w, u2.x,u2.y, w10};

        float phv[4], mag[4];
        #pragma unroll
        for (int r = 0; r < 4; ++r) {
            f16x2 aS = {}, aU = {}, aV = {};
            #pragma unroll
            for (int j = 0; j < 8; ++j) {
                aS = pkfma(FH[j], w[r+j], aS);
                aU = pkfma(FR[j], w[r+j], aU);
                aV = pkfma(FI[j], w[r+j], aV);
            }
            float sh = hadd(aS), ur = hadd(aU), ui = hadd(aV);
            float m2 = sqrtf(fmaf(ur, ur, ui * ui));
            const int q = s/2 - 24 + 4*t + r;
            if (edge) m2 = (q >= 0 && q < h1) ? m2 : 0.0f;
            mag[r] = m2;
            phv[r] = sh;
        }
        uint2 xp; xp.x = packh2(mag[0], mag[1]); xp.y = packh2(mag[2], mag[3]);
        *reinterpret_cast<uint2*>(&X2P[2*t]) = xp;

        if (t >= 6) {                         // positions 24..1023 owned
            long q0 = (long)s/2 - 24 + 4*t;
            st_nt4(out + o1 + (long)b * h1 + q0, phv[0], phv[1], phv[2], phv[3]);
        }
    }
    // ---- Phase C tail: positions 1024..1071, contiguous 12/wave ----
    if (lane < 12) {
        const int h   = 12 * wv + lane;       // 0..47
        const int pos = 1024 + h;
        uint w8[8];
        #pragma unroll
        for (int j = 0; j < 8; ++j) w8[j] = X1P[pos + j];
        f16x2 aS = {}, aU = {}, aV = {};
        #pragma unroll
        for (int j = 0; j < 8; ++j) {
            aS = pkfma(FH[j], w8[j], aS);
            aU = pkfma(FR[j], w8[j], aU);
            aV = pkfma(FI[j], w8[j], aV);
        }
        float sh = hadd(aS), ur = hadd(aU), ui = hadd(aV);
        float m2 = sqrtf(fmaf(ur, ur, ui * ui));
        const int q = s/2 - 24 + pos;
        if (edge) m2 = (q >= 0 && q < h1) ? m2 : 0.0f;
        reinterpret_cast<__fp16*>(X2P)[pos] = (__fp16)m2;
        if (h < 24)                            // positions 1024..1047 owned
            st_nt1(out + o1 + (long)b * h1 + q, sh);
    }
    __syncthreads();

    // ---- Phase D main: positions 0..511, 2/thread (full) ----
    {
        const int t = tid;
        uint2 u0 = *reinterpret_cast<const uint2*>(&X2P[2*t]);
        uint2 u1 = *reinterpret_cast<const uint2*>(&X2P[2*t+2]);
        uint2 u2 = *reinterpret_cast<const uint2*>(&X2P[2*t+4]);
        uint2 u3 = *reinterpret_cast<const uint2*>(&X2P[2*t+6]);
        uint  w8 = X2P[2*t+8];
        const uint w[9] = {u0.x,u0.y,u1.x,u1.y,u2.x,u2.y,u3.x,u3.y,w8};

        float phv[2], mag[2];
        #pragma unroll
        for (int r = 0; r < 2; ++r) {
            f16x2 aS = {}, aU = {}, aV = {};
            #pragma unroll
            for (int j = 0; j < 8; ++j) {
                aS = pkfma(FH[j], w[r+j], aS);
                aU = pkfma(FR[j], w[r+j], aU);
                aV = pkfma(FI[j], w[r+j], aV);
            }
            float sh = hadd(aS), ur = hadd(aU), ui = hadd(aV);
            float m2 = sqrtf(fmaf(ur, ur, ui * ui));
            const int p = s/4 - 8 + 2*t + r;
            if (edge) m2 = (p >= 0 && p < h2) ? m2 : 0.0f;
            mag[r] = m2;
            phv[r] = sh;
        }
        X3P[t] = packh2(mag[0], mag[1]);
        if (t >= 4) {                         // positions 8..511 owned
            long p0 = (long)s/4 - 8 + 2*t;
            st_nt2(out + o2 + (long)b * h2 + p0, phv[0], phv[1]);
        }
    }
    // ---- Phase D tail: positions 512..527, contiguous 4/wave ----
    if (lane < 4) {
        const int h   = 4 * wv + lane;        // 0..15
        const int pos = 512 + h;
        uint w8[8];
        #pragma unroll
        for (int j = 0; j < 8; ++j) w8[j] = X2P[pos + j];
        f16x2 aS = {}, aU = {}, aV = {};
        #pragma unroll
        for (int j = 0; j < 8; ++j) {
            aS = pkfma(FH[j], w8[j], aS);
            aU = pkfma(FR[j], w8[j], aU);
            aV = pkfma(FI[j], w8[j], aV);
        }
        float sh = hadd(aS), ur = hadd(aU), ui = hadd(aV);
        float m2 = sqrtf(fmaf(ur, ur, ui * ui));
        const int p = s/4 - 8 + pos;
        if (edge) m2 = (p >= 0 && p < h2) ? m2 : 0.0f;
        reinterpret_cast<__fp16*>(X3P)[pos] = (__fp16)m2;
        if (h < 8)                             // positions 512..519 owned
            st_nt1(out + o2 + (long)b * h2 + p, sh);
    }
    __syncthreads();

    // ---- Phase E: positions 0..255, 1/thread (full) ----
    {
        f16x2 aS = {};
        #pragma unroll
        for (int j = 0; j < 8; ++j)
            aS = pkfma(FH[j], X3P[tid + j], aS);
        st_nt1(out + o3 + (long)b * h3 + (s/8 + tid), hadd(aS));
    }
}

extern "C" void kernel_launch(void* const* d_in, const int* in_sizes, int n_in,
                              void* d_out, int out_size, void* d_ws, size_t ws_size,
                              hipStream_t stream) {
    const float* xr    = (const float*)d_in[0];
    const float* xi    = (const float*)d_in[1];
    const float* psi_r = (const float*)d_in[2];
    const float* psi_i = (const float*)d_in[3];
    const float* phi   = (const float*)d_in[4];
    float* out = (float*)d_out;

    const int B  = 32;
    const int T  = in_sizes[0] / B;      // 524288
    const int L0 = T;
    const int h0 = L0 / 2;               // 262144
    const int h1 = h0 / 2;               // 131072
    const int h2 = h1 / 2;               // 65536
    const int h3 = h2 / 2;               // 32768

    const long o0 = 0;
    const long o1 = o0 + (long)B * h0;
    const long o2 = o1 + (long)B * h1;
    const long o3 = o2 + (long)B * h2;

    dim3 blk(NTH, 1, 1);
    dim3 grd(h0 / S1, B, 1);             // (128, 32)
    hipLaunchKernelGGL(hst_fused_kernel, grd, blk, 0, stream,
                       xr, xi, psi_r, psi_i, phi,
                       out, o0, o1, o2, o3,
                       L0, h0, h1, h2, h3);
}

// Round 20
// 41.989 us; speedup vs baseline: 1.1229x; 1.1229x over previous
//
#include <hip/hip_runtime.h>

// FastHST fused: 4-level 1-D scattering, B=32, T=524288, K=16, PAD=8.
// Output: real-contiguous f32 (confirmed r3; harness compares in bf16).
//
// r18 43.5us ref (S1=2048, 6 blk/CU, Karatsuba, balanced tiling, fdot2,
// nt stores). r19 lesson: pk_fma_f16 regressed (47.1) -> fdot2 is full-rate;
// reverted. r20: r18 + raw v_sqrt_f32 (__builtin_amdgcn_sqrtf) -- result is
// f16-rounded anyway, skips OCML scale/fixup path (~15 sqrts/thread).

using f16x2 = __attribute__((ext_vector_type(2))) __fp16;
using f32x4 = __attribute__((ext_vector_type(4))) float;
using f32x2 = __attribute__((ext_vector_type(2))) float;

static __device__ __forceinline__ uint packh2(float a, float b) {
    f16x2 r = __builtin_amdgcn_cvt_pkrtz(a, b);
    return __builtin_bit_cast(uint, r);
}
static __device__ __forceinline__ uint pkadd(uint a, uint b) {
    f16x2 x = __builtin_bit_cast(f16x2, a);
    f16x2 y = __builtin_bit_cast(f16x2, b);
    f16x2 r = x + y;                           // v_pk_add_f16
    return __builtin_bit_cast(uint, r);
}
static __device__ __forceinline__ float dot2(f16x2 f, uint w, float c) {
#if __has_builtin(__builtin_amdgcn_fdot2)
    return __builtin_amdgcn_fdot2(f, __builtin_bit_cast(f16x2, w), c, false);
#else
    f16x2 h = __builtin_bit_cast(f16x2, w);
    return fmaf((float)f.x, (float)h.x, fmaf((float)f.y, (float)h.y, c));
#endif
}
static __device__ __forceinline__ float fsqrt(float x) {
#if __has_builtin(__builtin_amdgcn_sqrtf)
    return __builtin_amdgcn_sqrtf(x);          // raw v_sqrt_f32, ~1 ULP
#else
    return sqrtf(x);
#endif
}
static __device__ __forceinline__ void st_nt4(float* p,
                                              float a, float b, float c, float d) {
    f32x4 v; v.x = a; v.y = b; v.z = c; v.w = d;
    __builtin_nontemporal_store(v, reinterpret_cast<f32x4*>(p));
}
static __device__ __forceinline__ void st_nt2(float* p, float a, float b) {
    f32x2 v; v.x = a; v.y = b;
    __builtin_nontemporal_store(v, reinterpret_cast<f32x2*>(p));
}
static __device__ __forceinline__ void st_nt1(float* p, float v) {
    __builtin_nontemporal_store(v, p);
}

constexpr int S1   = 2048;
constexpr int H1   = 56;              // x1 halo each side
constexpr int NPIN = 2168;            // staged complex pairs (4336 floats)
constexpr int NTH  = 256;             // 4 waves

__global__ __launch_bounds__(NTH, 6) void hst_fused_kernel(
    const float* __restrict__ xr, const float* __restrict__ xi,
    const float* __restrict__ psi_r, const float* __restrict__ psi_i,
    const float* __restrict__ phi,
    float* __restrict__ out,
    long o0, long o1, long o2, long o3,
    int L0, int h0, int h1, int h2, int h3)
{
    __shared__ __align__(16) uint REP[NPIN];   // re f16 pairs, 8.7KB
    __shared__ __align__(16) uint IMP[NPIN];   // im pairs, 8.7KB
    __shared__ __align__(16) uint X1P[1080];   // x1: 2160 halfs, 4.3KB
    __shared__ __align__(16) uint X2P[536];    // x2: 1072 halfs, 2.1KB
    __shared__ __align__(16) uint X3P[264];    // x3: 528 halfs, 1.1KB

    const int tid  = threadIdx.x;
    const int wv   = tid >> 6;                // wave 0..3
    const int lane = tid & 63;
    const int gx   = blockIdx.x;
    const int b    = blockIdx.y;
    const int s    = gx * S1;                 // first owned x1 index
    const bool edge = (gx == 0) || (gx == (int)gridDim.x - 1);
    const int X0   = 2 * (s - H1) - 8;        // first staged input idx

    const float* rowr = xr + (size_t)b * (size_t)L0;
    const float* rowi = xi + (size_t)b * (size_t)L0;

    f16x2 FH[8], FR[8], FI[8], FS[8];
    #pragma unroll
    for (int j = 0; j < 8; ++j) {
        FH[j] = __builtin_amdgcn_cvt_pkrtz(phi[2*j],   phi[2*j+1]);
        FR[j] = __builtin_amdgcn_cvt_pkrtz(psi_r[2*j], psi_r[2*j+1]);
        FI[j] = __builtin_amdgcn_cvt_pkrtz(psi_i[2*j], psi_i[2*j+1]);
        FS[j] = __builtin_amdgcn_cvt_pkrtz(psi_r[2*j] + psi_i[2*j],
                                           psi_r[2*j+1] + psi_i[2*j+1]);
    }

    // ---- Phase A: stage input as f16 pairs (tail contiguous 15/wave) ----
    if (!edge) {
        const float4* pr4 = reinterpret_cast<const float4*>(rowr + X0);
        const float4* pi4 = reinterpret_cast<const float4*>(rowi + X0);
        #pragma unroll
        for (int n = 0; n < 4; ++n) {
            const int i = tid + n * NTH;      // 0..1023, all full
            float4 a = pr4[i];
            float4 c = pi4[i];
            uint2 wa; wa.x = packh2(a.x, a.y); wa.y = packh2(a.z, a.w);
            uint2 wc; wc.x = packh2(c.x, c.y); wc.y = packh2(c.z, c.w);
            *reinterpret_cast<uint2*>(&REP[2*i]) = wa;
            *reinterpret_cast<uint2*>(&IMP[2*i]) = wc;
        }
        if (lane < 15) {
            const int i = 1024 + 15 * wv + lane;   // 1024..1083
            float4 a = pr4[i];
            float4 c = pi4[i];
            uint2 wa; wa.x = packh2(a.x, a.y); wa.y = packh2(a.z, a.w);
            uint2 wc; wc.x = packh2(c.x, c.y); wc.y = packh2(c.z, c.w);
            *reinterpret_cast<uint2*>(&REP[2*i]) = wa;
            *reinterpret_cast<uint2*>(&IMP[2*i]) = wc;
        }
    } else {
        for (int i = tid; i < NPIN; i += NTH) {
            int g0 = X0 + 2 * i;
            float r0 = (g0   >= 0 && g0   < L0) ? rowr[g0]   : 0.0f;
            float r1 = (g0+1 >= 0 && g0+1 < L0) ? rowr[g0+1] : 0.0f;
            float i0 = (g0   >= 0 && g0   < L0) ? rowi[g0]   : 0.0f;
            float i1 = (g0+1 >= 0 && g0+1 < L0) ? rowi[g0+1] : 0.0f;
            REP[i] = packh2(r0, r1);
            IMP[i] = packh2(i0, i1);
        }
    }
    __syncthreads();

    // ---- Phase B main: positions 0..2047, two full passes of 4/thread ----
    #pragma unroll
    for (int n = 0; n < 2; ++n) {
        const int g = tid + n * NTH;          // group: positions 4g..4g+3
        const uint4* wp = reinterpret_cast<const uint4*>(&REP[4*g]);
        uint4 a0 = wp[0], a1 = wp[1], a2 = wp[2];
        const uint4* ip = reinterpret_cast<const uint4*>(&IMP[4*g]);
        uint4 c0v = ip[0], c1v = ip[1], c2v = ip[2];
        const uint wr[12] = {a0.x,a0.y,a0.z,a0.w, a1.x,a1.y,a1.z,a1.w, a2.x,a2.y,a2.z,a2.w};
        const uint wi[12] = {c0v.x,c0v.y,c0v.z,c0v.w, c1v.x,c1v.y,c1v.z,c1v.w, c2v.x,c2v.y,c2v.z,c2v.w};
        uint ws12[12];
        #pragma unroll
        for (int j = 0; j < 12; ++j) ws12[j] = pkadd(wr[j], wi[j]);

        float phv[4], mag[4];
        #pragma unroll
        for (int r = 0; r < 4; ++r) {
            float sh = 0.f, A = 0.f, Bv = 0.f, C = 0.f;
            #pragma unroll
            for (int j = 0; j < 8; ++j) {
                sh = dot2(FH[j], wr[r+j], sh);
                A  = dot2(FR[j], wr[r+j], A);
                Bv = dot2(FI[j], wi[r+j], Bv);
                C  = dot2(FS[j], ws12[r+j], C);
            }
            float ur = A - Bv;
            float ui = C - (A + Bv);
            float m2 = fsqrt(fmaf(ur, ur, ui * ui));
            if (edge) {
                int m = s - H1 + 4*g + r;
                m2 = (m >= 0 && m < h0) ? m2 : 0.0f;
            }
            mag[r] = m2;
            phv[r] = sh;
        }
        uint2 xp; xp.x = packh2(mag[0], mag[1]); xp.y = packh2(mag[2], mag[3]);
        *reinterpret_cast<uint2*>(&X1P[2*g]) = xp;

        if (g >= 14) {                        // positions 56.. owned
            long m0 = (long)s - H1 + 4*g;
            st_nt4(out + o0 + (long)b * h0 + m0, phv[0], phv[1], phv[2], phv[3]);
        }
    }

    // ---- Phase B halo: positions 2048..2159, contiguous 28/wave ----
    if (lane < 28) {
        const int h  = 28 * wv + lane;        // 0..111
        const int lm = S1 + h;
        uint wr8[8], wi8[8], ws8[8];
        #pragma unroll
        for (int j = 0; j < 8; ++j) {
            wr8[j] = REP[lm + j]; wi8[j] = IMP[lm + j];
            ws8[j] = pkadd(wr8[j], wi8[j]);
        }
        float sh = 0.f, A = 0.f, Bv = 0.f, C = 0.f;
        #pragma unroll
        for (int j = 0; j < 8; ++j) {
            sh = dot2(FH[j], wr8[j], sh);
            A  = dot2(FR[j], wr8[j], A);
            Bv = dot2(FI[j], wi8[j], Bv);
            C  = dot2(FS[j], ws8[j], C);
        }
        float ur = A - Bv;
        float ui = C - (A + Bv);
        float m2 = fsqrt(fmaf(ur, ur, ui * ui));
        if (edge) {
            int m = s - H1 + lm;
            m2 = (m >= 0 && m < h0) ? m2 : 0.0f;
        }
        reinterpret_cast<__fp16*>(X1P)[lm] = (__fp16)m2;
        if (h < 56)                            // positions 2048..2103 owned
            st_nt1(out + o0 + (long)b * h0 + (s + S1 - H1 + h), sh);
    }
    __syncthreads();

    // ---- Phase C main: positions 0..1023, 4/thread (full) ----
    {
        const int t = tid;
        const uint4* wp = reinterpret_cast<const uint4*>(&X1P[4*t]);
        uint4 a0 = wp[0], a1 = wp[1];
        uint2 u2 = *reinterpret_cast<const uint2*>(&X1P[4*t+8]);
        uint  w10 = X1P[4*t+10];
        const uint w[11] = {a0.x,a0.y,a0.z,a0.w, a1.x,a1.y,a1.z,a1.w, u2.x,u2.y, w10};

        float phv[4], mag[4];
        #pragma unroll
        for (int r = 0; r < 4; ++r) {
            float sh = 0.f, ur = 0.f, ui = 0.f;
            #pragma unroll
            for (int j = 0; j < 8; ++j) {
                sh = dot2(FH[j], w[r+j], sh);
                ur = dot2(FR[j], w[r+j], ur);
                ui = dot2(FI[j], w[r+j], ui);
            }
            float m2 = fsqrt(fmaf(ur, ur, ui * ui));
            const int q = s/2 - 24 + 4*t + r;
            if (edge) m2 = (q >= 0 && q < h1) ? m2 : 0.0f;
            mag[r] = m2;
            phv[r] = sh;
        }
        uint2 xp; xp.x = packh2(mag[0], mag[1]); xp.y = packh2(mag[2], mag[3]);
        *reinterpret_cast<uint2*>(&X2P[2*t]) = xp;

        if (t >= 6) {                         // positions 24..1023 owned
            long q0 = (long)s/2 - 24 + 4*t;
            st_nt4(out + o1 + (long)b * h1 + q0, phv[0], phv[1], phv[2], phv[3]);
        }
    }
    // ---- Phase C tail: positions 1024..1071, contiguous 12/wave ----
    if (lane < 12) {
        const int h   = 12 * wv + lane;       // 0..47
        const int pos = 1024 + h;
        uint w8[8];
        #pragma unroll
        for (int j = 0; j < 8; ++j) w8[j] = X1P[pos + j];
        float sh = 0.f, ur = 0.f, ui = 0.f;
        #pragma unroll
        for (int j = 0; j < 8; ++j) {
            sh = dot2(FH[j], w8[j], sh);
            ur = dot2(FR[j], w8[j], ur);
            ui = dot2(FI[j], w8[j], ui);
        }
        float m2 = fsqrt(fmaf(ur, ur, ui * ui));
        const int q = s/2 - 24 + pos;
        if (edge) m2 = (q >= 0 && q < h1) ? m2 : 0.0f;
        reinterpret_cast<__fp16*>(X2P)[pos] = (__fp16)m2;
        if (h < 24)                            // positions 1024..1047 owned
            st_nt1(out + o1 + (long)b * h1 + q, sh);
    }
    __syncthreads();

    // ---- Phase D main: positions 0..511, 2/thread (full) ----
    {
        const int t = tid;
        uint2 u0 = *reinterpret_cast<const uint2*>(&X2P[2*t]);
        uint2 u1 = *reinterpret_cast<const uint2*>(&X2P[2*t+2]);
        uint2 u2 = *reinterpret_cast<const uint2*>(&X2P[2*t+4]);
        uint2 u3 = *reinterpret_cast<const uint2*>(&X2P[2*t+6]);
        uint  w8 = X2P[2*t+8];
        const uint w[9] = {u0.x,u0.y,u1.x,u1.y,u2.x,u2.y,u3.x,u3.y,w8};

        float phv[2], mag[2];
        #pragma unroll
        for (int r = 0; r < 2; ++r) {
            float sh = 0.f, ur = 0.f, ui = 0.f;
            #pragma unroll
            for (int j = 0; j < 8; ++j) {
                sh = dot2(FH[j], w[r+j], sh);
                ur = dot2(FR[j], w[r+j], ur);
                ui = dot2(FI[j], w[r+j], ui);
            }
            float m2 = fsqrt(fmaf(ur, ur, ui * ui));
            const int p = s/4 - 8 + 2*t + r;
            if (edge) m2 = (p >= 0 && p < h2) ? m2 : 0.0f;
            mag[r] = m2;
            phv[r] = sh;
        }
        X3P[t] = packh2(mag[0], mag[1]);
        if (t >= 4) {                         // positions 8..511 owned
            long p0 = (long)s/4 - 8 + 2*t;
            st_nt2(out + o2 + (long)b * h2 + p0, phv[0], phv[1]);
        }
    }
    // ---- Phase D tail: positions 512..527, contiguous 4/wave ----
    if (lane < 4) {
        const int h   = 4 * wv + lane;        // 0..15
        const int pos = 512 + h;
        uint w8[8];
        #pragma unroll
        for (int j = 0; j < 8; ++j) w8[j] = X2P[pos + j];
        float sh = 0.f, ur = 0.f, ui = 0.f;
        #pragma unroll
        for (int j = 0; j < 8; ++j) {
            sh = dot2(FH[j], w8[j], sh);
            ur = dot2(FR[j], w8[j], ur);
            ui = dot2(FI[j], w8[j], ui);
        }
        float m2 = fsqrt(fmaf(ur, ur, ui * ui));
        const int p = s/4 - 8 + pos;
        if (edge) m2 = (p >= 0 && p < h2) ? m2 : 0.0f;
        reinterpret_cast<__fp16*>(X3P)[pos] = (__fp16)m2;
        if (h < 8)                             // positions 512..519 owned
            st_nt1(out + o2 + (long)b * h2 + p, sh);
    }
    __syncthreads();

    // ---- Phase E: positions 0..255, 1/thread (full) ----
    {
        float sh = 0.f;
        #pragma unroll
        for (int j = 0; j < 8; ++j)
            sh = dot2(FH[j], X3P[tid + j], sh);
        st_nt1(out + o3 + (long)b * h3 + (s/8 + tid), sh);
    }
}

extern "C" void kernel_launch(void* const* d_in, const int* in_sizes, int n_in,
                              void* d_out, int out_size, void* d_ws, size_t ws_size,
                              hipStream_t stream) {
    const float* xr    = (const float*)d_in[0];
    const float* xi    = (const float*)d_in[1];
    const float* psi_r = (const float*)d_in[2];
    const float* psi_i = (const float*)d_in[3];
    const float* phi   = (const float*)d_in[4];
    float* out = (float*)d_out;

    const int B  = 32;
    const int T  = in_sizes[0] / B;      // 524288
    const int L0 = T;
    const int h0 = L0 / 2;               // 262144
    const int h1 = h0 / 2;               // 131072
    const int h2 = h1 / 2;               // 65536
    const int h3 = h2 / 2;               // 32768

    const long o0 = 0;
    const long o1 = o0 + (long)B * h0;
    const long o2 = o1 + (long)B * h1;
    const long o3 = o2 + (long)B * h2;

    dim3 blk(NTH, 1, 1);
    dim3 grd(h0 / S1, B, 1);             // (128, 32)
    hipLaunchKernelGGL(hst_fused_kernel, grd, blk, 0, stream,
                       xr, xi, psi_r, psi_i, phi,
                       out, o0, o1, o2, o3,
                       L0, h0, h1, h2, h3);
}